// Round 1
// baseline (132.793 us; speedup 1.0000x reference)
//
#include <hip/hip_runtime.h>
#include <stddef.h>

#define IMG_N 4096

typedef float vf4 __attribute__((ext_vector_type(4)));

// LDS layout (float offsets), total 8752 floats = 35,008 B -> 4 blocks/CU.
// Phase plan (3 barriers):
//   P1: load 80x80 + DWT1 + DWT2   (200 threads, 4x8 input patch each)
//   P2: conv7 (tid 0-255) || conv5 (256-319) || DWT3 (320-369)
//   P3: conv3 + IDWT3 + IDWT2 fused (tid 0-127; LL2P lives in registers)
//   P4: IDWT1 -> out (all 512), NT float4 stores
// Alias: raw HH1 dead after P2 (conv7) -> slot hosts LL1P (32x36).
#define S_HH1   0        // 1760 (40 x stride 44)
#define S_LH1   1760     // 1760
#define S_HL1   3520     // 1760
#define S_LL2   5280     // 400  (20x20)
#define S_LH2   5680     // 400
#define S_HL2   6080     // 400
#define S_HH2   6480     // 400
#define S_HH1C  6880     // 1152 (32 x stride 36)
#define S_HH2C  8032     // 320  (16 x stride 20)
#define S_LL3   8352     // 100  (10x10)
#define S_LH3   8452
#define S_HL3   8552
#define S_HH3   8652
#define S_TOTAL 8752
#define S_LL1P  S_HH1    // 1152 (32 x stride 36), written P3, read P4

__global__ __launch_bounds__(512, 8) void haar_fused(
    const float* __restrict__ x,
    const float* __restrict__ w3, const float* __restrict__ b3,
    const float* __restrict__ w5, const float* __restrict__ b5,
    const float* __restrict__ w7, const float* __restrict__ b7,
    float* __restrict__ out)
{
    __shared__ __align__(16) float sm[S_TOTAL];
    const int tid = threadIdx.x;
    const int bx = blockIdx.x, by = blockIdx.y;
    const int R0 = by * 64, C0 = bx * 64;

    float* HH1  = sm + S_HH1;
    float* LH1  = sm + S_LH1;   float* HL1 = sm + S_HL1;
    float* LL2  = sm + S_LL2;   float* LH2 = sm + S_LH2;
    float* HL2  = sm + S_HL2;   float* HH2 = sm + S_HH2;
    float* HH1C = sm + S_HH1C;  float* HH2C = sm + S_HH2C;
    float* LL3  = sm + S_LL3;   float* LH3 = sm + S_LH3;
    float* HL3  = sm + S_HL3;   float* HH3 = sm + S_HH3;
    float* LL1P = sm + S_LL1P;

    // ==== P1: global load + DWT1 + DWT2. 200 items = 20 row-groups x 10 col-groups.
    // Each item: 4x8 pixel patch (8 dwordx4 loads) -> 2 rows x 4 cols of L1 coeffs
    // (LH/HL/HH to LDS, LL kept in registers) -> 1 row x 2 cols of L2 coeffs to LDS.
    const bool interior = (by >= 1) && (by <= 62) && (bx >= 1) && (bx <= 62);
    if (tid < 200) {
        const int u = tid / 10, g = tid % 10;
        float v[4][8];
        if (interior) {
            const float* p = x + (size_t)(R0 - 8 + 4 * u) * IMG_N + (C0 - 8 + 8 * g);
            #pragma unroll
            for (int k = 0; k < 4; ++k) {
                float4 a = *(const float4*)(p + (size_t)k * IMG_N);
                float4 b = *(const float4*)(p + (size_t)k * IMG_N + 4);
                v[k][0] = a.x; v[k][1] = a.y; v[k][2] = a.z; v[k][3] = a.w;
                v[k][4] = b.x; v[k][5] = b.y; v[k][6] = b.z; v[k][7] = b.w;
            }
        } else {
            const int gr = R0 - 8 + 4 * u, gc = C0 - 8 + 8 * g;
            #pragma unroll
            for (int k = 0; k < 4; ++k) {
                const int grk = gr + k;
                const bool rv = (grk >= 0 && grk < IMG_N);
                #pragma unroll
                for (int j = 0; j < 8; ++j) {
                    const int gcj = gc + j;
                    v[k][j] = (rv && gcj >= 0 && gcj < IMG_N)
                              ? x[(size_t)grk * IMG_N + gcj] : 0.0f;
                }
            }
        }
        float ll0[4], ll1[4];
        // row-pair 0: input rows 0,1 -> L1 row 2u
        {
            float4 lhv, hlv, hhv;
            float a = v[0][0], b = v[0][1], c = v[1][0], d = v[1][1];
            ll0[0] = (a+b+c+d)*0.5f; lhv.x = (a+b-c-d)*0.5f;
            hlv.x = (a-b+c-d)*0.5f;  hhv.x = (a-b-c+d)*0.5f;
            a = v[0][2]; b = v[0][3]; c = v[1][2]; d = v[1][3];
            ll0[1] = (a+b+c+d)*0.5f; lhv.y = (a+b-c-d)*0.5f;
            hlv.y = (a-b+c-d)*0.5f;  hhv.y = (a-b-c+d)*0.5f;
            a = v[0][4]; b = v[0][5]; c = v[1][4]; d = v[1][5];
            ll0[2] = (a+b+c+d)*0.5f; lhv.z = (a+b-c-d)*0.5f;
            hlv.z = (a-b+c-d)*0.5f;  hhv.z = (a-b-c+d)*0.5f;
            a = v[0][6]; b = v[0][7]; c = v[1][6]; d = v[1][7];
            ll0[3] = (a+b+c+d)*0.5f; lhv.w = (a+b-c-d)*0.5f;
            hlv.w = (a-b+c-d)*0.5f;  hhv.w = (a-b-c+d)*0.5f;
            const int o = (2 * u) * 44 + 4 * g;
            *(float4*)(LH1 + o) = lhv; *(float4*)(HL1 + o) = hlv;
            *(float4*)(HH1 + o) = hhv;
        }
        // row-pair 1: input rows 2,3 -> L1 row 2u+1
        {
            float4 lhv, hlv, hhv;
            float a = v[2][0], b = v[2][1], c = v[3][0], d = v[3][1];
            ll1[0] = (a+b+c+d)*0.5f; lhv.x = (a+b-c-d)*0.5f;
            hlv.x = (a-b+c-d)*0.5f;  hhv.x = (a-b-c+d)*0.5f;
            a = v[2][2]; b = v[2][3]; c = v[3][2]; d = v[3][3];
            ll1[1] = (a+b+c+d)*0.5f; lhv.y = (a+b-c-d)*0.5f;
            hlv.y = (a-b+c-d)*0.5f;  hhv.y = (a-b-c+d)*0.5f;
            a = v[2][4]; b = v[2][5]; c = v[3][4]; d = v[3][5];
            ll1[2] = (a+b+c+d)*0.5f; lhv.z = (a+b-c-d)*0.5f;
            hlv.z = (a-b+c-d)*0.5f;  hhv.z = (a-b-c+d)*0.5f;
            a = v[2][6]; b = v[2][7]; c = v[3][6]; d = v[3][7];
            ll1[3] = (a+b+c+d)*0.5f; lhv.w = (a+b-c-d)*0.5f;
            hlv.w = (a-b+c-d)*0.5f;  hhv.w = (a-b-c+d)*0.5f;
            const int o = (2 * u + 1) * 44 + 4 * g;
            *(float4*)(LH1 + o) = lhv; *(float4*)(HL1 + o) = hlv;
            *(float4*)(HH1 + o) = hhv;
        }
        // DWT2 on the in-register 2x4 LL block -> L2 row u, cols 2g..2g+1
        {
            float2 l2ll, l2lh, l2hl, l2hh;
            float a = ll0[0], b = ll0[1], c = ll1[0], d = ll1[1];
            l2ll.x = (a+b+c+d)*0.5f; l2lh.x = (a+b-c-d)*0.5f;
            l2hl.x = (a-b+c-d)*0.5f; l2hh.x = (a-b-c+d)*0.5f;
            a = ll0[2]; b = ll0[3]; c = ll1[2]; d = ll1[3];
            l2ll.y = (a+b+c+d)*0.5f; l2lh.y = (a+b-c-d)*0.5f;
            l2hl.y = (a-b+c-d)*0.5f; l2hh.y = (a-b-c+d)*0.5f;
            const int o2 = u * 20 + 2 * g;
            *(float2*)(LL2 + o2) = l2ll; *(float2*)(LH2 + o2) = l2lh;
            *(float2*)(HL2 + o2) = l2hl; *(float2*)(HH2 + o2) = l2hh;
        }
    }
    __syncthreads();   // B1

    // ==== P2: conv7 (0-255) || conv5 (256-319) || DWT3 (320-369) ====
    if (tid < 256) {
        // conv7 on HH1, 32x32 in-tile outputs, 1x4 strip per thread.
        const int i = tid >> 3;
        const int j0 = (tid & 7) << 2;
        const float bias = b7[0];
        float a0 = bias, a1 = bias, a2 = bias, a3 = bias;
        #pragma unroll
        for (int dy = 0; dy < 7; ++dy) {
            const float* rp = HH1 + (i + dy + 1) * 44 + j0;
            float4 A = *(const float4*)(rp);
            float4 B = *(const float4*)(rp + 4);
            float4 C = *(const float4*)(rp + 8);
            const float* wr = w7 + dy * 7;
            float q0 = wr[0], q1 = wr[1], q2 = wr[2], q3 = wr[3], q4 = wr[4],
                  q5 = wr[5], q6 = wr[6];
            a0 += q0*A.y + q1*A.z + q2*A.w + q3*B.x + q4*B.y + q5*B.z + q6*B.w;
            a1 += q0*A.z + q1*A.w + q2*B.x + q3*B.y + q4*B.z + q5*B.w + q6*C.x;
            a2 += q0*A.w + q1*B.x + q2*B.y + q3*B.z + q4*B.w + q5*C.x + q6*C.y;
            a3 += q0*B.x + q1*B.y + q2*B.z + q3*B.w + q4*C.x + q5*C.y + q6*C.z;
        }
        *(float4*)(HH1C + i * 36 + j0) = make_float4(a0, a1, a2, a3);
    } else if (tid < 320) {
        // conv5 on HH2: 16x16 in-tile outputs, 1x4 strips (64 strips).
        const int s = tid - 256;
        const int i = s >> 2;
        const int j0 = (s & 3) << 2;
        const float bias = b5[0];
        float a0 = bias, a1 = bias, a2 = bias, a3 = bias;
        #pragma unroll
        for (int dy = 0; dy < 5; ++dy) {
            const float* rp = HH2 + (i + dy) * 20 + j0;
            float4 A = *(const float4*)(rp);
            float4 B = *(const float4*)(rp + 4);
            const float* wr = w5 + dy * 5;
            float q0 = wr[0], q1 = wr[1], q2 = wr[2], q3 = wr[3], q4 = wr[4];
            a0 += q0*A.x + q1*A.y + q2*A.z + q3*A.w + q4*B.x;
            a1 += q0*A.y + q1*A.z + q2*A.w + q3*B.x + q4*B.y;
            a2 += q0*A.z + q1*A.w + q2*B.x + q3*B.y + q4*B.z;
            a3 += q0*A.w + q1*B.x + q2*B.y + q3*B.z + q4*B.w;
        }
        *(float4*)(HH2C + i * 20 + j0) = make_float4(a0, a1, a2, a3);
    } else if (tid < 370) {
        // DWT3: LL2 (20x20 @20) -> level-3 10x10 @10. 50 items = 10 rows x 5 pairs.
        const int t = tid - 320;
        const int u = t / 5, v2 = (t % 5) * 2;
        const float* rp = LL2 + (2 * u) * 20 + 2 * v2;
        float4 t0 = *(const float4*)(rp);
        float4 c0 = *(const float4*)(rp + 20);
        const int o = u * 10 + v2;
        *(float2*)(LL3 + o) = make_float2((t0.x + t0.y + c0.x + c0.y) * 0.5f,
                                          (t0.z + t0.w + c0.z + c0.w) * 0.5f);
        *(float2*)(LH3 + o) = make_float2((t0.x + t0.y - c0.x - c0.y) * 0.5f,
                                          (t0.z + t0.w - c0.z - c0.w) * 0.5f);
        *(float2*)(HL3 + o) = make_float2((t0.x - t0.y + c0.x - c0.y) * 0.5f,
                                          (t0.z - t0.w + c0.z - c0.w) * 0.5f);
        *(float2*)(HH3 + o) = make_float2((t0.x - t0.y - c0.x + c0.y) * 0.5f,
                                          (t0.z - t0.w - c0.z + c0.w) * 0.5f);
    }
    __syncthreads();   // B2

    // ==== P3: conv3 + IDWT3 + IDWT2 fused (tid 0-127) ====
    // Thread (p,c) produces LL2P[p][2c..2c+1] in registers, then the four
    // IDWT2 outputs they feed: rows 2p,2p+1 x col-pairs 2c,2c+1 -> LL1P.
    if (tid < 128) {
        const int p = tid >> 3, c = tid & 7;
        const int r = p >> 1;
        const float sr = (p & 1) ? -1.0f : 1.0f;
        float hh = b3[0];
        #pragma unroll
        for (int dy = 0; dy < 3; ++dy) {
            const float* row = HH3 + (r + dy) * 10 + c;
            const float* wr = w3 + dy * 3;
            hh += wr[0]*row[0] + wr[1]*row[1] + wr[2]*row[2];
        }
        const int li3 = (r + 1) * 10 + (c + 1);
        const float lo3 = LL3[li3] + sr * LH3[li3];
        const float hi3 = HL3[li3] + sr * hh;
        const float v0 = (lo3 + hi3) * 0.5f;   // LL2P[p][2c]
        const float v1 = (lo3 - hi3) * 0.5f;   // LL2P[p][2c+1]

        const int li2 = (p + 2) * 20 + (2 * c + 2);
        float2 lh2 = *(const float2*)(LH2 + li2);
        float2 hl2 = *(const float2*)(HL2 + li2);
        float2 hc  = *(const float2*)(HH2C + p * 20 + 2 * c);
        #pragma unroll
        for (int q = 0; q < 2; ++q) {
            const float s2 = q ? -1.0f : 1.0f;
            const float lo0 = v0 + s2 * lh2.x;
            const float hi0 = hl2.x + s2 * hc.x;
            const float lo1 = v1 + s2 * lh2.y;
            const float hi1 = hl2.y + s2 * hc.y;
            *(float4*)(LL1P + (2 * p + q) * 36 + 4 * c) =
                make_float4((lo0 + hi0) * 0.5f, (lo0 - hi0) * 0.5f,
                            (lo1 + hi1) * 0.5f, (lo1 - hi1) * 0.5f);
        }
    }
    __syncthreads();   // B3

    // ==== P4: IDWT1 -> out (64x64), NT float4 stores. 1024 items / 2 rounds ====
    #pragma unroll
    for (int k = 0; k < 2; ++k) {
        const int idx = tid + 512 * k;
        const int p = idx >> 4;
        const int c2 = (idx & 15) * 2;
        const int r = p >> 1;
        const float sr = (p & 1) ? -1.0f : 1.0f;
        const int li = (r + 4) * 44 + (c2 + 4);
        const int ci = r * 36 + c2;
        float2 llp = *(const float2*)(LL1P + ci);
        float2 lh  = *(const float2*)(LH1 + li);
        float2 hl  = *(const float2*)(HL1 + li);
        float2 hhc = *(const float2*)(HH1C + ci);
        float lo0 = llp.x + sr * lh.x;
        float hi0 = hl.x + sr * hhc.x;
        float lo1 = llp.y + sr * lh.y;
        float hi1 = hl.y + sr * hhc.y;
        vf4 o = { (lo0 + hi0) * 0.5f, (lo0 - hi0) * 0.5f,
                  (lo1 + hi1) * 0.5f, (lo1 - hi1) * 0.5f };
        __builtin_nontemporal_store(
            o, (vf4*)(out + (size_t)(R0 + p) * IMG_N + C0 + 2 * c2));
    }
}

extern "C" void kernel_launch(void* const* d_in, const int* in_sizes, int n_in,
                              void* d_out, int out_size, void* d_ws, size_t ws_size,
                              hipStream_t stream) {
    (void)in_sizes; (void)n_in; (void)out_size; (void)d_ws; (void)ws_size;
    const float* x  = (const float*)d_in[0];
    const float* w3 = (const float*)d_in[1];
    const float* b3 = (const float*)d_in[2];
    const float* w5 = (const float*)d_in[3];
    const float* b5 = (const float*)d_in[4];
    const float* w7 = (const float*)d_in[5];
    const float* b7 = (const float*)d_in[6];
    float* out = (float*)d_out;

    dim3 grid(IMG_N / 64, IMG_N / 64);     // 64x64 tiles of 64x64 output px
    dim3 block(512);
    haar_fused<<<grid, block, 0, stream>>>(x, w3, b3, w5, b5, w7, b7, out);
}

// Round 2
// 131.155 us; speedup vs baseline: 1.0125x; 1.0125x over previous
//
#include <hip/hip_runtime.h>
#include <stddef.h>

#define IMG_N 4096

typedef float vf4 __attribute__((ext_vector_type(4)));

// 64-wide x 32-tall output tiles, 256 threads, 8 blocks/CU.
// LDS layout (float offsets), total 5104 floats = 20,416 B.
// Phase plan (3 barriers):
//   P1: load 80x48 + DWT1 + DWT2   (120 items of 4x8 patch, spread over 4 waves)
//   P2: conv7 (tid 0-127) || conv5 (128-159) || DWT3 (160-189)
//   P3: conv3 + IDWT3 + IDWT2 fused (tid 0-63; LL2P lives in registers)
//   P4: IDWT1 -> out (64x32), NT float4 stores, 2 rounds
// Alias: raw HH1 dead after P2 (conv7) -> slot hosts LL1P (16 x stride 36).
#define S_HH1   0        // 1056 (24 rows x stride 44, 40 used)
#define S_LH1   1056     // 1056
#define S_HL1   2112     // 1056
#define S_LL2   3168     // 240  (12 x 20)
#define S_LH2   3408     // 240
#define S_HL2   3648     // 240
#define S_HH2   3888     // 240
#define S_HH1C  4128     // 576  (16 x stride 36, 32 used)
#define S_HH2C  4704     // 160  (8 x 20, 16 used)
#define S_LL3   4864     // 60   (6 x 10)
#define S_LH3   4924
#define S_HL3   4984
#define S_HH3   5044
#define S_TOTAL 5104
#define S_LL1P  S_HH1    // 576 (16 x stride 36), written P3, read P4

__global__ __launch_bounds__(256, 8) void haar_fused(
    const float* __restrict__ x,
    const float* __restrict__ w3, const float* __restrict__ b3,
    const float* __restrict__ w5, const float* __restrict__ b5,
    const float* __restrict__ w7, const float* __restrict__ b7,
    float* __restrict__ out)
{
    __shared__ __align__(16) float sm[S_TOTAL];
    const int tid = threadIdx.x;
    const int bx = blockIdx.x, by = blockIdx.y;
    const int R0 = by * 32, C0 = bx * 64;

    float* HH1  = sm + S_HH1;
    float* LH1  = sm + S_LH1;   float* HL1 = sm + S_HL1;
    float* LL2  = sm + S_LL2;   float* LH2 = sm + S_LH2;
    float* HL2  = sm + S_HL2;   float* HH2 = sm + S_HH2;
    float* HH1C = sm + S_HH1C;  float* HH2C = sm + S_HH2C;
    float* LL3  = sm + S_LL3;   float* LH3 = sm + S_LH3;
    float* HL3  = sm + S_HL3;   float* HH3 = sm + S_HH3;
    float* LL1P = sm + S_LL1P;

    // ==== P1: global load + DWT1 + DWT2. 120 items = 12 row-groups x 10 col-groups.
    // Spread 30 items per wave (4 waves) for more VMEM issue streams.
    // Each item: 4x8 pixel patch (8 dwordx4 loads) -> 2 rows x 4 cols of L1 coeffs
    // (LH/HL/HH to LDS, LL kept in registers) -> 1 row x 2 cols of L2 coeffs to LDS.
    const bool interior = (by >= 1) && (by <= 126) && (bx >= 1) && (bx <= 62);
    const int lane = tid & 63, wv = tid >> 6;
    if (lane < 30) {
        const int item = wv * 30 + lane;
        const int u = item / 10, g = item % 10;
        float v[4][8];
        if (interior) {
            const float* p = x + (size_t)(R0 - 8 + 4 * u) * IMG_N + (C0 - 8 + 8 * g);
            #pragma unroll
            for (int k = 0; k < 4; ++k) {
                float4 a = *(const float4*)(p + (size_t)k * IMG_N);
                float4 b = *(const float4*)(p + (size_t)k * IMG_N + 4);
                v[k][0] = a.x; v[k][1] = a.y; v[k][2] = a.z; v[k][3] = a.w;
                v[k][4] = b.x; v[k][5] = b.y; v[k][6] = b.z; v[k][7] = b.w;
            }
        } else {
            const int gr = R0 - 8 + 4 * u, gc = C0 - 8 + 8 * g;
            #pragma unroll
            for (int k = 0; k < 4; ++k) {
                const int grk = gr + k;
                const bool rv = (grk >= 0 && grk < IMG_N);
                #pragma unroll
                for (int j = 0; j < 8; ++j) {
                    const int gcj = gc + j;
                    v[k][j] = (rv && gcj >= 0 && gcj < IMG_N)
                              ? x[(size_t)grk * IMG_N + gcj] : 0.0f;
                }
            }
        }
        float ll0[4], ll1[4];
        // row-pair 0: input rows 0,1 -> L1 row 2u
        {
            float4 lhv, hlv, hhv;
            float a = v[0][0], b = v[0][1], c = v[1][0], d = v[1][1];
            ll0[0] = (a+b+c+d)*0.5f; lhv.x = (a+b-c-d)*0.5f;
            hlv.x = (a-b+c-d)*0.5f;  hhv.x = (a-b-c+d)*0.5f;
            a = v[0][2]; b = v[0][3]; c = v[1][2]; d = v[1][3];
            ll0[1] = (a+b+c+d)*0.5f; lhv.y = (a+b-c-d)*0.5f;
            hlv.y = (a-b+c-d)*0.5f;  hhv.y = (a-b-c+d)*0.5f;
            a = v[0][4]; b = v[0][5]; c = v[1][4]; d = v[1][5];
            ll0[2] = (a+b+c+d)*0.5f; lhv.z = (a+b-c-d)*0.5f;
            hlv.z = (a-b+c-d)*0.5f;  hhv.z = (a-b-c+d)*0.5f;
            a = v[0][6]; b = v[0][7]; c = v[1][6]; d = v[1][7];
            ll0[3] = (a+b+c+d)*0.5f; lhv.w = (a+b-c-d)*0.5f;
            hlv.w = (a-b+c-d)*0.5f;  hhv.w = (a-b-c+d)*0.5f;
            const int o = (2 * u) * 44 + 4 * g;
            *(float4*)(LH1 + o) = lhv; *(float4*)(HL1 + o) = hlv;
            *(float4*)(HH1 + o) = hhv;
        }
        // row-pair 1: input rows 2,3 -> L1 row 2u+1
        {
            float4 lhv, hlv, hhv;
            float a = v[2][0], b = v[2][1], c = v[3][0], d = v[3][1];
            ll1[0] = (a+b+c+d)*0.5f; lhv.x = (a+b-c-d)*0.5f;
            hlv.x = (a-b+c-d)*0.5f;  hhv.x = (a-b-c+d)*0.5f;
            a = v[2][2]; b = v[2][3]; c = v[3][2]; d = v[3][3];
            ll1[1] = (a+b+c+d)*0.5f; lhv.y = (a+b-c-d)*0.5f;
            hlv.y = (a-b+c-d)*0.5f;  hhv.y = (a-b-c+d)*0.5f;
            a = v[2][4]; b = v[2][5]; c = v[3][4]; d = v[3][5];
            ll1[2] = (a+b+c+d)*0.5f; lhv.z = (a+b-c-d)*0.5f;
            hlv.z = (a-b+c-d)*0.5f;  hhv.z = (a-b-c+d)*0.5f;
            a = v[2][6]; b = v[2][7]; c = v[3][6]; d = v[3][7];
            ll1[3] = (a+b+c+d)*0.5f; lhv.w = (a+b-c-d)*0.5f;
            hlv.w = (a-b+c-d)*0.5f;  hhv.w = (a-b-c+d)*0.5f;
            const int o = (2 * u + 1) * 44 + 4 * g;
            *(float4*)(LH1 + o) = lhv; *(float4*)(HL1 + o) = hlv;
            *(float4*)(HH1 + o) = hhv;
        }
        // DWT2 on the in-register 2x4 LL block -> L2 row u, cols 2g..2g+1
        {
            float2 l2ll, l2lh, l2hl, l2hh;
            float a = ll0[0], b = ll0[1], c = ll1[0], d = ll1[1];
            l2ll.x = (a+b+c+d)*0.5f; l2lh.x = (a+b-c-d)*0.5f;
            l2hl.x = (a-b+c-d)*0.5f; l2hh.x = (a-b-c+d)*0.5f;
            a = ll0[2]; b = ll0[3]; c = ll1[2]; d = ll1[3];
            l2ll.y = (a+b+c+d)*0.5f; l2lh.y = (a+b-c-d)*0.5f;
            l2hl.y = (a-b+c-d)*0.5f; l2hh.y = (a-b-c+d)*0.5f;
            const int o2 = u * 20 + 2 * g;
            *(float2*)(LL2 + o2) = l2ll; *(float2*)(LH2 + o2) = l2lh;
            *(float2*)(HL2 + o2) = l2hl; *(float2*)(HH2 + o2) = l2hh;
        }
    }
    __syncthreads();   // B1

    // ==== P2: conv7 (0-127) || conv5 (128-159) || DWT3 (160-189) ====
    if (tid < 128) {
        // conv7 on HH1, 32x16 in-tile outputs, 1x4 strip per thread.
        const int i = tid >> 3;
        const int j0 = (tid & 7) << 2;
        const float bias = b7[0];
        float a0 = bias, a1 = bias, a2 = bias, a3 = bias;
        #pragma unroll
        for (int dy = 0; dy < 7; ++dy) {
            const float* rp = HH1 + (i + dy + 1) * 44 + j0;
            float4 A = *(const float4*)(rp);
            float4 B = *(const float4*)(rp + 4);
            float4 C = *(const float4*)(rp + 8);
            const float* wr = w7 + dy * 7;
            float q0 = wr[0], q1 = wr[1], q2 = wr[2], q3 = wr[3], q4 = wr[4],
                  q5 = wr[5], q6 = wr[6];
            a0 += q0*A.y + q1*A.z + q2*A.w + q3*B.x + q4*B.y + q5*B.z + q6*B.w;
            a1 += q0*A.z + q1*A.w + q2*B.x + q3*B.y + q4*B.z + q5*B.w + q6*C.x;
            a2 += q0*A.w + q1*B.x + q2*B.y + q3*B.z + q4*B.w + q5*C.x + q6*C.y;
            a3 += q0*B.x + q1*B.y + q2*B.z + q3*B.w + q4*C.x + q5*C.y + q6*C.z;
        }
        *(float4*)(HH1C + i * 36 + j0) = make_float4(a0, a1, a2, a3);
    } else if (tid < 160) {
        // conv5 on HH2: 16x8 in-tile outputs, 1x4 strips (32 strips).
        const int s = tid - 128;
        const int i = s >> 2;
        const int j0 = (s & 3) << 2;
        const float bias = b5[0];
        float a0 = bias, a1 = bias, a2 = bias, a3 = bias;
        #pragma unroll
        for (int dy = 0; dy < 5; ++dy) {
            const float* rp = HH2 + (i + dy) * 20 + j0;
            float4 A = *(const float4*)(rp);
            float4 B = *(const float4*)(rp + 4);
            const float* wr = w5 + dy * 5;
            float q0 = wr[0], q1 = wr[1], q2 = wr[2], q3 = wr[3], q4 = wr[4];
            a0 += q0*A.x + q1*A.y + q2*A.z + q3*A.w + q4*B.x;
            a1 += q0*A.y + q1*A.z + q2*A.w + q3*B.x + q4*B.y;
            a2 += q0*A.z + q1*A.w + q2*B.x + q3*B.y + q4*B.z;
            a3 += q0*A.w + q1*B.x + q2*B.y + q3*B.z + q4*B.w;
        }
        *(float4*)(HH2C + i * 20 + j0) = make_float4(a0, a1, a2, a3);
    } else if (tid < 190) {
        // DWT3: LL2 (12x20 @20) -> level-3 10 wide x 6 tall @10. 30 items.
        const int t = tid - 160;
        const int u = t / 5, v2 = (t % 5) * 2;
        const float* rp = LL2 + (2 * u) * 20 + 2 * v2;
        float4 t0 = *(const float4*)(rp);
        float4 c0 = *(const float4*)(rp + 20);
        const int o = u * 10 + v2;
        *(float2*)(LL3 + o) = make_float2((t0.x + t0.y + c0.x + c0.y) * 0.5f,
                                          (t0.z + t0.w + c0.z + c0.w) * 0.5f);
        *(float2*)(LH3 + o) = make_float2((t0.x + t0.y - c0.x - c0.y) * 0.5f,
                                          (t0.z + t0.w - c0.z - c0.w) * 0.5f);
        *(float2*)(HL3 + o) = make_float2((t0.x - t0.y + c0.x - c0.y) * 0.5f,
                                          (t0.z - t0.w + c0.z - c0.w) * 0.5f);
        *(float2*)(HH3 + o) = make_float2((t0.x - t0.y - c0.x + c0.y) * 0.5f,
                                          (t0.z - t0.w - c0.z + c0.w) * 0.5f);
    }
    __syncthreads();   // B2

    // ==== P3: conv3 + IDWT3 + IDWT2 fused (tid 0-63) ====
    // Thread (p,c) produces LL2P[p][2c..2c+1] in registers, then the four
    // IDWT2 outputs they feed: rows 2p,2p+1 x col-pairs 2c,2c+1 -> LL1P.
    if (tid < 64) {
        const int p = tid >> 3, c = tid & 7;
        const int r = p >> 1;
        const float sr = (p & 1) ? -1.0f : 1.0f;
        float hh = b3[0];
        #pragma unroll
        for (int dy = 0; dy < 3; ++dy) {
            const float* row = HH3 + (r + dy) * 10 + c;
            const float* wr = w3 + dy * 3;
            hh += wr[0]*row[0] + wr[1]*row[1] + wr[2]*row[2];
        }
        const int li3 = (r + 1) * 10 + (c + 1);
        const float lo3 = LL3[li3] + sr * LH3[li3];
        const float hi3 = HL3[li3] + sr * hh;
        const float v0 = (lo3 + hi3) * 0.5f;   // LL2P[p][2c]
        const float v1 = (lo3 - hi3) * 0.5f;   // LL2P[p][2c+1]

        const int li2 = (p + 2) * 20 + (2 * c + 2);
        float2 lh2 = *(const float2*)(LH2 + li2);
        float2 hl2 = *(const float2*)(HL2 + li2);
        float2 hc  = *(const float2*)(HH2C + p * 20 + 2 * c);
        #pragma unroll
        for (int q = 0; q < 2; ++q) {
            const float s2 = q ? -1.0f : 1.0f;
            const float lo0 = v0 + s2 * lh2.x;
            const float hi0 = hl2.x + s2 * hc.x;
            const float lo1 = v1 + s2 * lh2.y;
            const float hi1 = hl2.y + s2 * hc.y;
            *(float4*)(LL1P + (2 * p + q) * 36 + 4 * c) =
                make_float4((lo0 + hi0) * 0.5f, (lo0 - hi0) * 0.5f,
                            (lo1 + hi1) * 0.5f, (lo1 - hi1) * 0.5f);
        }
    }
    __syncthreads();   // B3

    // ==== P4: IDWT1 -> out (64x32), NT float4 stores. 512 items / 2 rounds ====
    #pragma unroll
    for (int k = 0; k < 2; ++k) {
        const int idx = tid + 256 * k;
        const int p = idx >> 4;
        const int c2 = (idx & 15) * 2;
        const int r = p >> 1;
        const float sr = (p & 1) ? -1.0f : 1.0f;
        const int li = (r + 4) * 44 + (c2 + 4);
        const int ci = r * 36 + c2;
        float2 llp = *(const float2*)(LL1P + ci);
        float2 lh  = *(const float2*)(LH1 + li);
        float2 hl  = *(const float2*)(HL1 + li);
        float2 hhc = *(const float2*)(HH1C + ci);
        float lo0 = llp.x + sr * lh.x;
        float hi0 = hl.x + sr * hhc.x;
        float lo1 = llp.y + sr * lh.y;
        float hi1 = hl.y + sr * hhc.y;
        vf4 o = { (lo0 + hi0) * 0.5f, (lo0 - hi0) * 0.5f,
                  (lo1 + hi1) * 0.5f, (lo1 - hi1) * 0.5f };
        __builtin_nontemporal_store(
            o, (vf4*)(out + (size_t)(R0 + p) * IMG_N + C0 + 2 * c2));
    }
}

extern "C" void kernel_launch(void* const* d_in, const int* in_sizes, int n_in,
                              void* d_out, int out_size, void* d_ws, size_t ws_size,
                              hipStream_t stream) {
    (void)in_sizes; (void)n_in; (void)out_size; (void)d_ws; (void)ws_size;
    const float* x  = (const float*)d_in[0];
    const float* w3 = (const float*)d_in[1];
    const float* b3 = (const float*)d_in[2];
    const float* w5 = (const float*)d_in[3];
    const float* b5 = (const float*)d_in[4];
    const float* w7 = (const float*)d_in[5];
    const float* b7 = (const float*)d_in[6];
    float* out = (float*)d_out;

    dim3 grid(IMG_N / 64, IMG_N / 32);     // 64x128 tiles of 64x32 output px
    dim3 block(256);
    haar_fused<<<grid, block, 0, stream>>>(x, w3, b3, w5, b5, w7, b7, out);
}